// Round 1
// baseline (6343.382 us; speedup 1.0000x reference)
//
#include <hip/hip_runtime.h>
#include <hip/hip_fp16.h>

// Persistent fused GRU + value head for MI355X.
// T=512,B=256,I=64,H=512. Grid = 256 wgs = NB(16 batch groups) x NH(16 hidden slices).
// Weight slices live in registers as MFMA B-fragments; h exchanged per step via
// device-coherent buffer + per-group monotonic counter barrier.

#define T_  512
#define B_  256
#define I_  64
#define H_  512
#define NBG 16   // batch groups
#define NHS 16   // hidden slices per group (sync fan-in)
#define BT  16   // batch per group   (MFMA M)
#define HS  32   // hidden units per slice
#define NCOL 96  // 3*HS preact columns: [r(0:32) | z(32:64) | n(64:96)]
#define WAVES 6
#define BLOCK 384

typedef _Float16 f16;
typedef _Float16 f16x8 __attribute__((ext_vector_type(8)));
typedef float    f32x4 __attribute__((ext_vector_type(4)));

__device__ __forceinline__ float sigmoid_f(float x) { return 1.f / (1.f + __expf(-x)); }
__device__ __forceinline__ float tanh_f(float x) {
    float e2 = __expf(2.f * x);           // inf-safe: 1 - 2/(e2+1) -> +/-1 at extremes
    return 1.f - 2.f / (e2 + 1.f);
}

__global__ __launch_bounds__(BLOCK) void gru_persistent(
    const float* __restrict__ X, const float* __restrict__ Wih,
    const float* __restrict__ Whh, const float* __restrict__ bih,
    const float* __restrict__ bhh, const float* __restrict__ vw,
    const float* __restrict__ bias, float* __restrict__ Vout,
    float* __restrict__ hbuf, unsigned int* __restrict__ ctr)
{
    // block -> (batch group g, slice j); members of a group share blockIdx%8
    // so the HW round-robin block->XCD mapping keeps a sync group on one XCD (heuristic only).
    const int blk  = blockIdx.x;
    const int g    = (blk & 7) * 2 + (blk >> 7);   // [0,16)
    const int j    = (blk >> 3) & 15;              // [0,16)
    const int b0   = g * BT;
    const int tid  = threadIdx.x;
    const int wv   = tid >> 6;                     // wave = owned 16-col N-tile
    const int lane = tid & 63;
    const int quad = lane >> 4;
    const int mrow = lane & 15;

    __shared__ f16   sh_h[BT][H_ + 8];     // h_{t-1} as fp16, +8 pad (16B) kills bank conflicts
    __shared__ f16   sh_x[BT][I_ + 8];
    __shared__ float sh_hold[BT][HS];      // own-slice h_{t-1} in fp32 (for z*h term)
    __shared__ float sh_Ph[BT][NCOL + 4];  // hidden-proj preacts
    __shared__ float sh_Pin[BT][NCOL + 4]; // input-proj preacts (n-gate needs them separate)
    __shared__ float sh_hnew[BT][HS];
    __shared__ float sh_bih[NCOL];
    __shared__ float sh_bhh[NCOL];
    __shared__ float sh_vw[HS];

    // ---- stationary MFMA B-fragments (16x16x32_f16: B[k][n], n=lane&15, k=quad*8+e) ----
    const int ncol = wv * 16 + mrow;                           // local preact column
    const int grow = (ncol >> 5) * H_ + HS * j + (ncol & 31);  // global row in (3H,*) weights
    f16x8 wfrag[16];
    #pragma unroll
    for (int kt = 0; kt < 16; kt++) {
        const float* src = Whh + grow * H_ + kt * 32 + quad * 8;
        #pragma unroll
        for (int e = 0; e < 8; e++) wfrag[kt][e] = (f16)src[e];
    }
    f16x8 wfragX[2];
    #pragma unroll
    for (int kt = 0; kt < 2; kt++) {
        const float* src = Wih + grow * I_ + kt * 32 + quad * 8;
        #pragma unroll
        for (int e = 0; e < 8; e++) wfragX[kt][e] = (f16)src[e];
    }

    if (tid < NCOL) {
        int c  = tid;
        int gr = (c >> 5) * H_ + HS * j + (c & 31);
        sh_bih[c] = bih[gr];
        sh_bhh[c] = bhh[gr];
    } else if (tid < NCOL + HS) {
        int u = tid - NCOL;
        sh_vw[u] = vw[HS * j + u];
    }
    const float bias0 = bias[0];
    __syncthreads();

    #pragma unroll 1
    for (int t = 0; t < T_; t++) {
        // ---- 1. wait until all NHS slices of h_{t-1} are published ----
        if (tid == 0 && t > 0) {
            const unsigned target = (unsigned)(NHS * t);
            while (__hip_atomic_load(&ctr[g], __ATOMIC_ACQUIRE, __HIP_MEMORY_SCOPE_AGENT) < target)
                __builtin_amdgcn_s_sleep(2);
        }
        __syncthreads();

        // ---- 2. coherent read of full h_{t-1} for our batch group; cached read of X_t ----
        const float* hprev = hbuf + ((t & 1) ^ 1) * (B_ * H_);  // t=0 reads zeroed buffer 1
        for (int e = tid; e < BT * H_; e += BLOCK) {
            int bb = e >> 9, k = e & (H_ - 1);
            float v = __hip_atomic_load(&hprev[(b0 + bb) * H_ + k],
                                        __ATOMIC_RELAXED, __HIP_MEMORY_SCOPE_AGENT);
            sh_h[bb][k] = (f16)v;
            unsigned u = (unsigned)(k - HS * j);
            if (u < (unsigned)HS) sh_hold[bb][u] = v;
        }
        for (int e = tid; e < BT * I_; e += BLOCK) {
            int bb = e >> 6, i = e & (I_ - 1);
            sh_x[bb][i] = (f16)X[t * (B_ * I_) + (b0 + bb) * I_ + i];
        }
        __syncthreads();

        // ---- 3. MFMA: preacts = h @ Whh_slice^T  and  x @ Wih_slice^T ----
        f32x4 acch  = {0.f, 0.f, 0.f, 0.f};
        f32x4 accin = {0.f, 0.f, 0.f, 0.f};
        #pragma unroll
        for (int kt = 0; kt < 16; kt++) {
            f16x8 a = *(const f16x8*)&sh_h[mrow][kt * 32 + quad * 8];  // A[m=lane&15][k=quad*8+e]
            acch = __builtin_amdgcn_mfma_f32_16x16x32_f16(a, wfrag[kt], acch, 0, 0, 0);
        }
        #pragma unroll
        for (int kt = 0; kt < 2; kt++) {
            f16x8 a = *(const f16x8*)&sh_x[mrow][kt * 32 + quad * 8];
            accin = __builtin_amdgcn_mfma_f32_16x16x32_f16(a, wfragX[kt], accin, 0, 0, 0);
        }
        #pragma unroll
        for (int r = 0; r < 4; r++) {                 // C/D: col=lane&15, row=quad*4+reg
            int m = quad * 4 + r;
            sh_Ph[m][ncol]  = acch[r];
            sh_Pin[m][ncol] = accin[r];
        }
        __syncthreads();

        // ---- 4. gates + h update (fp32), publish h_t slice coherently ----
        float* hcur = hbuf + (t & 1) * (B_ * H_);
        for (int e = tid; e < BT * HS; e += BLOCK) {
            int bb = e >> 5, u = e & (HS - 1);
            float pr   = sh_Pin[bb][u]      + sh_bih[u]      + sh_Ph[bb][u]      + sh_bhh[u];
            float pz   = sh_Pin[bb][32 + u] + sh_bih[32 + u] + sh_Ph[bb][32 + u] + sh_bhh[32 + u];
            float pnin = sh_Pin[bb][64 + u] + sh_bih[64 + u];
            float pnh  = sh_Ph[bb][64 + u]  + sh_bhh[64 + u];
            float r = sigmoid_f(pr);
            float z = sigmoid_f(pz);
            float n = tanh_f(pnin + r * pnh);
            float hn = (1.f - z) * n + z * sh_hold[bb][u];
            __hip_atomic_store(&hcur[(b0 + bb) * H_ + HS * j + u], hn,
                               __ATOMIC_RELAXED, __HIP_MEMORY_SCOPE_AGENT);
            sh_hnew[bb][u] = hn;
        }
        __syncthreads();  // per-wave vmcnt drain: slice stores complete before signal
        if (tid == 0)
            __hip_atomic_fetch_add(&ctr[g], 1u, __ATOMIC_RELEASE, __HIP_MEMORY_SCOPE_AGENT);

        // ---- 5. value-head partial: V[t,b] += dot(h_t[b, slice], vw[slice]) ----
        if (tid < BT) {
            float s = (j == 0) ? bias0 : 0.f;
            #pragma unroll
            for (int u = 0; u < HS; u++) s += sh_hnew[tid][u] * sh_vw[u];
            atomicAdd(&Vout[t * B_ + b0 + tid], s);
        }
    }
}

extern "C" void kernel_launch(void* const* d_in, const int* in_sizes, int n_in,
                              void* d_out, int out_size, void* d_ws, size_t ws_size,
                              hipStream_t stream) {
    const float* X    = (const float*)d_in[0];
    const float* Wih  = (const float*)d_in[1];
    const float* Whh  = (const float*)d_in[2];
    const float* bih  = (const float*)d_in[3];
    const float* bhh  = (const float*)d_in[4];
    const float* vw   = (const float*)d_in[5];
    const float* bias = (const float*)d_in[6];
    float* Vout = (float*)d_out;

    // ws layout: [0, 1MB) ping-pong h buffers (2 x B*H fp32), then NBG counters
    float* hbuf = (float*)d_ws;
    unsigned int* ctr = (unsigned int*)((char*)d_ws + (size_t)2 * B_ * H_ * sizeof(float));

    hipMemsetAsync(d_ws, 0, (size_t)2 * B_ * H_ * sizeof(float) + NBG * sizeof(unsigned int), stream);
    hipMemsetAsync(d_out, 0, (size_t)out_size * sizeof(float), stream);

    gru_persistent<<<256, BLOCK, 0, stream>>>(X, Wih, Whh, bih, bhh, vw, bias, Vout, hbuf, ctr);
}